// Round 3
// baseline (1193.160 us; speedup 1.0000x reference)
//
#include <hip/hip_runtime.h>
#include <math.h>

#define NNODE 10000
#define NEDGE 160000
#define KNB   16
#define K1    17
#define NT    10
#define TN    10
#define DF    128
#define CAP   64
#define NEG_BIG (-1e9f)

// base-2 log-domain constants
#define LOGQ2      (-3.32192809489f)   /* log2(0.1) */
#define KB_SCALE   (-14.4269504089f)   /* -10*log2e  */
#define CR_SCALE   (28.8539008178f)    /* +20*log2e  */
#define G_SCALE    (-0.069314718056f)  /* -ln2/10    */
#define LN2        0.69314718056f

#if defined(__has_builtin)
#if __has_builtin(__builtin_amdgcn_exp2f)
#define EXP2F(x) __builtin_amdgcn_exp2f(x)
#endif
#endif
#ifndef EXP2F
#define EXP2F(x) __expf((x) * LN2)
#endif
#define LOG2F(x) __log2f(x)

// single-wave workgroup "barrier": drain LDS queue; lockstep wave => all lanes' writes visible
#define WSYNC() asm volatile("s_waitcnt lgkmcnt(0)" ::: "memory")

// packed-fp32 helpers (compiler lowers to v_pk_*_f32)
__device__ __forceinline__ float2 pk_add(float2 a, float2 b) { return make_float2(a.x + b.x, a.y + b.y); }
__device__ __forceinline__ float2 pk_sub(float2 a, float2 b) { return make_float2(a.x - b.x, a.y - b.y); }
__device__ __forceinline__ float2 pk_mul(float2 a, float2 b) { return make_float2(a.x * b.x, a.y * b.y); }
__device__ __forceinline__ float2 pk_max(float2 a, float2 b) { return make_float2(fmaxf(a.x, b.x), fmaxf(a.y, b.y)); }
__device__ __forceinline__ float2 pk_fma(float2 a, float2 b, float2 c) { return make_float2(fmaf(a.x, b.x, c.x), fmaf(a.y, b.y, c.y)); }
__device__ __forceinline__ float2 pk_exp2(float2 a) { return make_float2(EXP2F(a.x), EXP2F(a.y)); }

// ---------- phase 1: edge bucketing ----------
__global__ void k_detect(const int* ei, int* flag) {
  if (blockIdx.x == 0 && threadIdx.x == 0) {
    int z = 0;
    for (int i = 0; i < 64; ++i) z |= ei[2 * i + 1];
    *flag = (z == 0) ? 1 : 0;  // 1 => int64 storage (high words all zero)
  }
}

__global__ void k_hist(const int* ei, const int* flag, int* cnt, int* ebuf) {
  int e = blockIdx.x * blockDim.x + threadIdx.x;
  if (e >= NEDGE) return;
  int wide = *flag;
  int s = wide ? ei[2 * e] : ei[e];
  int pos = atomicAdd(&cnt[s], 1);
  if (pos < CAP) ebuf[s * CAP + pos] = e;
}

// ---------- phase 2: per node, keep 16 smallest edge ids ----------
__global__ void k_select(const int* ei, const int* flag, const int* cnt, const int* ebuf,
                         int* nbrs, int* kcnt, int* Sg) {
  int i = blockIdx.x * blockDim.x + threadIdx.x;
  if (i >= NNODE) return;
  int wide = *flag;
  int c = cnt[i]; c = c > CAP ? CAP : c;
  int best[KNB];
  int m = 0;
  for (int j = 0; j < c; ++j) {
    int e = ebuf[i * CAP + j];
    if (m < KNB) {
      int p = m++;
      while (p > 0 && best[p - 1] > e) { best[p] = best[p - 1]; --p; }
      best[p] = e;
    } else if (e < best[KNB - 1]) {
      int p = KNB - 1;
      while (p > 0 && best[p - 1] > e) { best[p] = best[p - 1]; --p; }
      best[p] = e;
    }
  }
  kcnt[i] = m;
  Sg[i * K1 + 0] = i;
  for (int j = 0; j < KNB; ++j) {
    int v = 0;
    if (j < m) {
      int e = best[j];
      v = wide ? ei[2 * (NEDGE + e)] : ei[NEDGE + e];
    }
    nbrs[i * KNB + j] = v;
    Sg[i * K1 + 1 + j] = v;
  }
}

// ---------- phase 3: C1 as 17 row-bitmasks per node + A = rowsum/cnt1 ----------
__global__ void k_c1b(const int* nbrs, const int* kcnt, const int* Sg,
                      unsigned int* bitsG, float* Ag) {
  int i = blockIdx.x * blockDim.x + threadIdx.x;
  if (i >= NNODE) return;
  int S[K1];
#pragma unroll
  for (int a = 0; a < K1; ++a) S[a] = Sg[i * K1 + a];
  int kc = kcnt[i];
  float inv = 1.f / (float)(1 + kc);
  for (int a = 0; a < K1; ++a) {
    unsigned int bits = 0;
    bool va = (a == 0) || (a - 1 < kc);
    if (va) {
      int u = S[a];
      int ku = kcnt[u];
      for (int j = 0; j < ku; ++j) {
        int w = nbrs[u * KNB + j];
#pragma unroll
        for (int b = 0; b < K1; ++b) {
          if (((b == 0) || (b - 1 < kc)) && (S[b] == w)) bits |= (1u << b);
        }
      }
    }
    bitsG[i * K1 + a] = bits;
    Ag[i * K1 + a] = (float)__popc(bits) * inv;
  }
}

// ---------- phase 4: template stats ----------
__global__ void k_tstats(const float* tf, const float* tmpl, float* nF2, float* Bq) {
  int idx = blockIdx.x * blockDim.x + threadIdx.x;
  if (idx >= NT * TN) return;
  const float* fp = tf + (size_t)idx * DF;
  float s = 0.f;
  for (int d = 0; d < DF; ++d) { float v = fp[d]; s += v * v; }
  nF2[idx] = s;
  const float* cp = tmpl + (size_t)idx * TN;
  float s2 = 0.f;
  for (int c = 0; c < TN; ++c) { float v = cp[c]; s2 += v * v; }
  Bq[idx] = 0.1f * s2;
}

// ---------- phase 5: tiled dots: 64 nodes/block, x staged in LDS ----------
__global__ void __launch_bounds__(256) k_dots(const float* __restrict__ x,
                                              const float* __restrict__ tf,
                                              float* __restrict__ dots,
                                              float* __restrict__ nxv) {
  __shared__ float xs[64][DF];   // 32 KB
  const int nb = blockIdx.x * 64;
  const int nvalid = (NNODE - nb) < 64 ? (NNODE - nb) : 64;
  const int tid = threadIdx.x;
  {
    const float4* xg = (const float4*)(x + (size_t)nb * DF);
    float4* xl = (float4*)&xs[0][0];
    for (int i = tid; i < nvalid * (DF / 4); i += 256) xl[i] = xg[i];
  }
  __syncthreads();
  for (int o = tid; o < nvalid * (NT * TN); o += 256) {
    int n = o / (NT * TN);
    int tb = o - n * (NT * TN);
    const float4* fp = (const float4*)(tf + (size_t)tb * DF);
    const float4* xp = (const float4*)&xs[n][0];
    float s = 0.f;
#pragma unroll
    for (int d = 0; d < DF / 4; ++d) {
      float4 a = xp[d], f = fp[d];
      s += a.x * f.x + a.y * f.y + a.z * f.z + a.w * f.w;
    }
    dots[(size_t)(nb + n) * (NT * TN) + tb] = s;
  }
  if (tid < nvalid) {
    const float4* xp = (const float4*)&xs[tid][0];
    float s = 0.f;
#pragma unroll
    for (int d = 0; d < DF / 4; ++d) {
      float4 a = xp[d];
      s += a.x * a.x + a.y * a.y + a.z * a.z + a.w * a.w;
    }
    nxv[nb + tid] = s;
  }
}

// ---------- phase 6: FGW, column-major: lane = (pair, column), packed fp32 ----------
__global__ void __launch_bounds__(64) k_main(
    const float* __restrict__ tmpl,
    const int* __restrict__ kcnt, const int* __restrict__ Sg,
    const unsigned int* __restrict__ bitsG, const float* __restrict__ Ag,
    const float* __restrict__ dots, const float* __restrict__ nxv,
    const float* __restrict__ nF2, const float* __restrict__ Bq,
    float* __restrict__ out)
{
  __shared__ float KT[5][21][12];   // p-stride 252 ≡ 28 mod 32 -> disjoint bank groups
  __shared__ float fL[5][20];
  __shared__ float gL[5][12];
  __shared__ float accL[5][TN];

  const int lane = threadIdx.x;
  int p = lane / 10;
  const int b = lane - p * 10;
  const bool act = (p < 5);
  if (!act) p = 4;
  const int blk = blockIdx.x;
  const int node = blk >> 1;        // wave-uniform
  const int t = ((blk & 1) * 5) + p;
  const int tb = t * TN + b;

  const int kc = kcnt[node];
  const float cnt1 = (float)(1 + kc);
  const float inv_cnt1 = 1.f / cnt1;
  const float logp2v = -LOG2F(cnt1);
  const float lp2_r0 = ((b == 0) || (b - 1 < kc)) ? logp2v : NEG_BIG;  // row b
  const float lp2_r1 = ((9 + b) < kc) ? logp2v : NEG_BIG;              // row 10+b

  // C2 row b of template t (10 floats, 8B-aligned) as float2 pairs
  float2 c2v[5];
  {
    const float2* cp = (const float2*)(tmpl + (size_t)tb * TN);
#pragma unroll
    for (int j = 0; j < 5; ++j) c2v[j] = cp[j];
  }
  const float Bb = Bq[tb];
  const float nf2b = nF2[tb];

  float2 Kb2v[8]; float kb16;
  float2 Tpv[8];  float tp16;
  unsigned int bw[K1];     // wave-uniform C1 row bitmasks (SGPRs)
#pragma unroll
  for (int a = 0; a < K1; ++a) {
    bool va = (a == 0) || (a - 1 < kc);
    int sa = Sg[node * K1 + a];
    float Ma = (va ? (nxv[sa] - 2.f * dots[(size_t)sa * (NT * TN) + tb]) : 0.f) + nf2b;
    float base = 0.5f * Ma + Ag[node * K1 + a] + Bb;
    float kv = KB_SCALE * base;
    float tv = va ? (inv_cnt1 * 0.1f) : 0.f;
    if (a == 16) { kb16 = kv; tp16 = tv; }
    else if (a & 1) { Kb2v[a >> 1].y = kv; Tpv[a >> 1].y = tv; }
    else { Kb2v[a >> 1].x = kv; Tpv[a >> 1].x = tv; }
    bw[a] = bitsG[node * K1 + a];
  }

  float2 Kc2v[8]; float k16 = 0.f;
  float2 Kr0v[5], Kr1v[5];
  float g2 = 0.f;

#pragma unroll 1
  for (int k = 0; k < 6; ++k) {
    // ---- stage Tp columns into KT ----
    if (act) {
#pragma unroll
      for (int a = 0; a < 16; ++a) KT[p][a][b] = (a & 1) ? Tpv[a >> 1].y : Tpv[a >> 1].x;
      KT[p][16][b] = tp16;
    }
    WSYNC();
    // ---- R = Tp @ C2^T (col b per lane), packed dot ----
    float R[K1];
#pragma unroll
    for (int c = 0; c < K1; ++c) {
      const float* row = &KT[p][c][0];
      float4 u0 = *(const float4*)row;
      float4 u1 = *(const float4*)(row + 4);
      float2 u2 = *(const float2*)(row + 8);
      float2 acc = pk_mul(make_float2(u0.x, u0.y), c2v[0]);
      acc = pk_fma(make_float2(u0.z, u0.w), c2v[1], acc);
      acc = pk_fma(make_float2(u1.x, u1.y), c2v[2], acc);
      acc = pk_fma(make_float2(u1.z, u1.w), c2v[3], acc);
      acc = pk_fma(u2, c2v[4], acc);
      R[c] = acc.x + acc.y;
    }
    // ---- cross = C1 @ R via wave-uniform bitmask predication ----
#pragma unroll
    for (int a = 0; a < K1; ++a) {
      float cr = 0.f;
      unsigned int m = bw[a];
      if (m) {
#pragma unroll
        for (int c = 0; c < K1; ++c)
          if (m & (1u << c)) cr += R[c];
      }
      float base = (a == 16) ? kb16 : ((a & 1) ? Kb2v[a >> 1].y : Kb2v[a >> 1].x);
      float val = base + CR_SCALE * cr;
      if (a == 16) k16 = val;
      else if (a & 1) Kc2v[a >> 1].y = val;
      else Kc2v[a >> 1].x = val;
    }

    if (k == 5) {  // dist = sum_a Tp*(0.25*M + 0.5*G), G = G_SCALE * Kc2
      float acc = 0.f;
#pragma unroll
      for (int a = 0; a < K1; ++a) {
        bool va = (a == 0) || (a - 1 < kc);
        int sa = Sg[node * K1 + a];
        float Ma = (va ? (nxv[sa] - 2.f * dots[(size_t)sa * (NT * TN) + tb]) : 0.f) + nf2b;
        float kcv = (a == 16) ? k16 : ((a & 1) ? Kc2v[a >> 1].y : Kc2v[a >> 1].x);
        float tpv = (a == 16) ? tp16 : ((a & 1) ? Tpv[a >> 1].y : Tpv[a >> 1].x);
        acc += tpv * (0.25f * Ma + 0.5f * (G_SCALE * kcv));
      }
      if (act) accL[p][b] = acc;
      WSYNC();
      if (lane < 5) {
        float s = 0.f;
#pragma unroll
        for (int j = 0; j < TN; ++j) s += accL[lane][j];
        out[node * NT + (blk & 1) * 5 + lane] = s;
      }
      return;
    }

    // ---- transpose logK: stage columns, read rows b and 10+b ----
    WSYNC();
    if (act) {
#pragma unroll
      for (int a = 0; a < 16; ++a) KT[p][a][b] = (a & 1) ? Kc2v[a >> 1].y : Kc2v[a >> 1].x;
      KT[p][16][b] = k16;
    }
    WSYNC();
    {
      const float* r0 = &KT[p][b][0];
      float4 u0 = *(const float4*)r0;
      float4 u1 = *(const float4*)(r0 + 4);
      float2 u2 = *(const float2*)(r0 + 8);
      Kr0v[0] = make_float2(u0.x, u0.y); Kr0v[1] = make_float2(u0.z, u0.w);
      Kr0v[2] = make_float2(u1.x, u1.y); Kr0v[3] = make_float2(u1.z, u1.w);
      Kr0v[4] = u2;
      const float* r1 = &KT[p][10 + b][0];   // rows 17..20 = garbage, stores gated
      float4 w0 = *(const float4*)r1;
      float4 w1 = *(const float4*)(r1 + 4);
      float2 w2 = *(const float2*)(r1 + 8);
      Kr1v[0] = make_float2(w0.x, w0.y); Kr1v[1] = make_float2(w0.z, w0.w);
      Kr1v[2] = make_float2(w1.x, w1.y); Kr1v[3] = make_float2(w1.z, w1.w);
      Kr1v[4] = w2;
    }

    // ---- Sinkhorn: 20 iters ----
#pragma unroll 1
    for (int it = 0; it < 20; ++it) {
      float2 v[8]; float v16;
      if (it == 0) {
#pragma unroll
        for (int i = 0; i < 8; ++i) v[i] = Kc2v[i];
        v16 = k16;
      } else {
        float4 f0 = *(const float4*)&fL[p][0];
        float4 f1 = *(const float4*)&fL[p][4];
        float4 f2 = *(const float4*)&fL[p][8];
        float4 f3 = *(const float4*)&fL[p][12];
        float fx = fL[p][16];
        v[0] = pk_add(Kc2v[0], make_float2(f0.x, f0.y));
        v[1] = pk_add(Kc2v[1], make_float2(f0.z, f0.w));
        v[2] = pk_add(Kc2v[2], make_float2(f1.x, f1.y));
        v[3] = pk_add(Kc2v[3], make_float2(f1.z, f1.w));
        v[4] = pk_add(Kc2v[4], make_float2(f2.x, f2.y));
        v[5] = pk_add(Kc2v[5], make_float2(f2.z, f2.w));
        v[6] = pk_add(Kc2v[6], make_float2(f3.x, f3.y));
        v[7] = pk_add(Kc2v[7], make_float2(f3.z, f3.w));
        v16 = k16 + fx;
      }
      // column LSE (17 elems)
      float2 m01 = pk_max(pk_max(v[0], v[1]), pk_max(v[2], v[3]));
      float2 m23 = pk_max(pk_max(v[4], v[5]), pk_max(v[6], v[7]));
      float2 mm = pk_max(m01, m23);
      float mx = fmaxf(fmaxf(mm.x, mm.y), v16);
      float2 mxb = make_float2(mx, mx);
      float2 e0 = pk_exp2(pk_sub(v[0], mxb));
      float2 e1 = pk_exp2(pk_sub(v[1], mxb));
      float2 e2 = pk_exp2(pk_sub(v[2], mxb));
      float2 e3 = pk_exp2(pk_sub(v[3], mxb));
      float2 e4 = pk_exp2(pk_sub(v[4], mxb));
      float2 e5 = pk_exp2(pk_sub(v[5], mxb));
      float2 e6 = pk_exp2(pk_sub(v[6], mxb));
      float2 e7 = pk_exp2(pk_sub(v[7], mxb));
      float e16 = EXP2F(v16 - mx);
      float2 s01 = pk_add(pk_add(e0, e1), pk_add(e2, e3));
      float2 s23 = pk_add(pk_add(e4, e5), pk_add(e6, e7));
      float2 ss = pk_add(s01, s23);
      float s = ss.x + ss.y + e16;
      g2 = LOGQ2 - mx - LOG2F(s);
      if (act) gL[p][b] = g2;
      WSYNC();
      float2 gr[5];
      {
        float4 g0 = *(const float4*)&gL[p][0];
        float4 g1 = *(const float4*)&gL[p][4];
        float2 gx = *(const float2*)&gL[p][8];
        gr[0] = make_float2(g0.x, g0.y); gr[1] = make_float2(g0.z, g0.w);
        gr[2] = make_float2(g1.x, g1.y); gr[3] = make_float2(g1.z, g1.w);
        gr[4] = gx;
      }
      // row LSEs (rows b and 10+b, 10 elems each)
      float2 w0[5], w1[5];
#pragma unroll
      for (int j = 0; j < 5; ++j) w0[j] = pk_add(Kr0v[j], gr[j]);
#pragma unroll
      for (int j = 0; j < 5; ++j) w1[j] = pk_add(Kr1v[j], gr[j]);
      float2 a01 = pk_max(pk_max(w0[0], w0[1]), pk_max(w0[2], w0[3]));
      a01 = pk_max(a01, w0[4]);
      float mxa = fmaxf(a01.x, a01.y);
      float2 b01 = pk_max(pk_max(w1[0], w1[1]), pk_max(w1[2], w1[3]));
      b01 = pk_max(b01, w1[4]);
      float mxb2 = fmaxf(b01.x, b01.y);
      float2 mab = make_float2(mxa, mxa);
      float2 mbb = make_float2(mxb2, mxb2);
      float2 x0 = pk_exp2(pk_sub(w0[0], mab));
      float2 x1 = pk_exp2(pk_sub(w0[1], mab));
      float2 x2 = pk_exp2(pk_sub(w0[2], mab));
      float2 x3 = pk_exp2(pk_sub(w0[3], mab));
      float2 x4 = pk_exp2(pk_sub(w0[4], mab));
      float2 y0 = pk_exp2(pk_sub(w1[0], mbb));
      float2 y1 = pk_exp2(pk_sub(w1[1], mbb));
      float2 y2 = pk_exp2(pk_sub(w1[2], mbb));
      float2 y3 = pk_exp2(pk_sub(w1[3], mbb));
      float2 y4 = pk_exp2(pk_sub(w1[4], mbb));
      float2 sx = pk_add(pk_add(pk_add(x0, x1), pk_add(x2, x3)), x4);
      float2 sy = pk_add(pk_add(pk_add(y0, y1), pk_add(y2, y3)), y4);
      float sa2 = sx.x + sx.y;
      float sb2 = sy.x + sy.y;
      float fr0 = lp2_r0 - mxa - LOG2F(sa2);
      float fr1 = lp2_r1 - mxb2 - LOG2F(sb2);
      if (act) {
        fL[p][b] = fr0;
        if (b < 7) fL[p][10 + b] = fr1;
      }
      WSYNC();
    }

    // ---- FW update: Tp = (1-gam)*Tp + gam*exp2(f + g + logK) ----
    {
      float4 f0 = *(const float4*)&fL[p][0];
      float4 f1 = *(const float4*)&fL[p][4];
      float4 f2 = *(const float4*)&fL[p][8];
      float4 f3 = *(const float4*)&fL[p][12];
      float fx = fL[p][16];
      float2 fv[8];
      fv[0] = make_float2(f0.x, f0.y); fv[1] = make_float2(f0.z, f0.w);
      fv[2] = make_float2(f1.x, f1.y); fv[3] = make_float2(f1.z, f1.w);
      fv[4] = make_float2(f2.x, f2.y); fv[5] = make_float2(f2.z, f2.w);
      fv[6] = make_float2(f3.x, f3.y); fv[7] = make_float2(f3.z, f3.w);
      const float gam = 2.f / ((float)k + 2.f);
      const float om = 1.f - gam;
      const float2 g2b = make_float2(g2, g2);
      const float2 omb = make_float2(om, om);
      const float2 gmb = make_float2(gam, gam);
#pragma unroll
      for (int i = 0; i < 8; ++i) {
        float2 arg = pk_add(pk_add(Kc2v[i], fv[i]), g2b);
        float2 e = pk_exp2(arg);
        Tpv[i] = pk_fma(omb, Tpv[i], pk_mul(gmb, e));
      }
      tp16 = om * tp16 + gam * EXP2F(k16 + fx + g2);
    }
  }
}

extern "C" void kernel_launch(void* const* d_in, const int* in_sizes, int n_in,
                              void* d_out, int out_size, void* d_ws, size_t ws_size,
                              hipStream_t stream) {
  const float* x    = (const float*)d_in[0];
  const int*   ei   = (const int*)d_in[1];
  const float* tmpl = (const float*)d_in[2];
  const float* tf   = (const float*)d_in[3];
  float* out = (float*)d_out;

  int* cnt  = (int*)d_ws;
  int* ebuf = cnt + NNODE;
  int* nbrs = ebuf + (size_t)NNODE * CAP;
  int* kcnt = nbrs + (size_t)NNODE * KNB;
  int* Sg   = kcnt + NNODE;
  int* flag = Sg + (size_t)NNODE * K1;
  unsigned int* bits = (unsigned int*)(flag + 256);
  float* Ag   = (float*)(bits + (size_t)NNODE * K1);
  float* dots = Ag + (size_t)NNODE * K1;
  float* nxv  = dots + (size_t)NNODE * (NT * TN);
  float* nF2  = nxv + NNODE;
  float* Bq   = nF2 + NT * TN;

  hipMemsetAsync(cnt, 0, NNODE * sizeof(int), stream);
  k_detect<<<1, 64, 0, stream>>>(ei, flag);
  k_hist<<<(NEDGE + 255) / 256, 256, 0, stream>>>(ei, flag, cnt, ebuf);
  k_select<<<(NNODE + 255) / 256, 256, 0, stream>>>(ei, flag, cnt, ebuf, nbrs, kcnt, Sg);
  k_c1b<<<(NNODE + 255) / 256, 256, 0, stream>>>(nbrs, kcnt, Sg, bits, Ag);
  k_tstats<<<1, 128, 0, stream>>>(tf, tmpl, nF2, Bq);
  k_dots<<<(NNODE + 63) / 64, 256, 0, stream>>>(x, tf, dots, nxv);
  k_main<<<NNODE * 2, 64, 0, stream>>>(tmpl, kcnt, Sg, bits, Ag, dots, nxv, nF2, Bq, out);
}